// Round 13
// baseline (204.107 us; speedup 1.0000x reference)
//
#include <hip/hip_runtime.h>

typedef __attribute__((ext_vector_type(8))) short short8;
typedef __attribute__((ext_vector_type(16))) float f32x16;

// ws layout:
//   xt  [b=8][yy=66][c=64][xxh=66] f32, zero halo (memset)      (8.92 MB)
//   wt  [slab=72][e=8][n=128][8] bf16 B slabs, e = i&7          (2.36 MB)
// ft is GONE: features are computed on the fly inside the GEMM's A-staging.
#define XT_FLOATS 2230272u

typedef __attribute__((address_space(3))) unsigned int lds_u32_t;
typedef __attribute__((address_space(1))) const unsigned int g_u32_t;

__device__ __forceinline__ unsigned short f2bf(float x) {
    union { float f; unsigned u; } v; v.f = x;
    unsigned r = v.u + 0x7FFFu + ((v.u >> 16) & 1u);   // RNE bf16
    return (unsigned short)(r >> 16);
}

// 8-slot feature vector [silu, 6 bases, 0]; feat8(0) == the SAME-pad vector.
__device__ __forceinline__ void feat8(float p, unsigned short* uf) {
    float e   = __expf(-p);
    float sig = 1.f / (1.f + e);
    uf[0] = f2bf(p * sig);
    float u  = p * 1.5f + 4.5f;
    float fj = floorf(u);
    int   j0 = (int)fj;
    float t  = u - fj;
    bool  inr = (u >= 0.f) && (u < 9.f);
    float t2 = t * t, t3 = t2 * t;
    const float c16 = 1.f / 6.f;
    float r0 = t3 * c16;
    float r1 = (-3.f * t3 + 3.f * t2 + 3.f * t + 1.f) * c16;
    float r2 = (3.f * t3 - 6.f * t2 + 4.f) * c16;
    float s1 = 1.f - t;
    float r3 = s1 * s1 * s1 * c16;
#pragma unroll
    for (int g = 0; g < 6; ++g) {
        int r = j0 - g;
        float v = (r == 0) ? r0 : ((r == 1) ? r1 : ((r == 2) ? r2 : ((r == 3) ? r3 : 0.f)));
        uf[1 + g] = f2bf(inr ? v : 0.f);
    }
    uf[7] = 0;
}

// ---- Prep v5 (tiny): B-pack + x transpose only. ft eliminated. ----
// Block per line (512): (1) 144 B-chunks; (2) transpose x[line] 64px x 64c
// into xt[b][y+1][c][1+xx] (coalesced 256B row writes). Borders = memset 0.
__global__ __launch_bounds__(256)
void prep_all(const float* __restrict__ x,
              const float* __restrict__ bw, const float* __restrict__ sw,
              float* __restrict__ xt, unsigned short* __restrict__ wt) {
    const int blk = blockIdx.x;          // 0..511 = line
    const int tid = threadIdx.x;

    // (1) B prep into slab-chunk-major layout: wt[slab][i&7][n][8]
    if (tid < 144) {
        int idx = blk * 144 + tid;
        int o = idx / 576;
        int i = idx - o * 576;
        int slab = i >> 3, e = i & 7;
        union { unsigned short u[8]; uint4 v; } pk;
        pk.u[0] = f2bf(bw[o * 576 + i]);
        const float* s = sw + (size_t)(o * 576 + i) * 6;
#pragma unroll
        for (int f = 0; f < 6; ++f) pk.u[1 + f] = f2bf(s[f]);
        pk.u[7] = 0;
        *(uint4*)(wt + ((size_t)slab * 8192 + e * 1024 + o * 8)) = pk.v;
    }

    // (2) transpose x line -> xt rows
    __shared__ float Xl[64 * 65];
    const int b = blk >> 6, y = blk & 63;
    const float* xl = x + (size_t)blk * 4096;
    for (int f4 = tid; f4 < 1024; f4 += 256) {
        float4 v = ((const float4*)xl)[f4];
        int xx = f4 >> 4, c4 = (f4 & 15) << 2;
        Xl[(c4 + 0) * 65 + xx] = v.x;
        Xl[(c4 + 1) * 65 + xx] = v.y;
        Xl[(c4 + 2) * 65 + xx] = v.z;
        Xl[(c4 + 3) * 65 + xx] = v.w;
    }
    __syncthreads();
    const int lane = tid & 63;
    const int w    = tid >> 6;           // 0..3
#pragma unroll
    for (int r = 0; r < 16; ++r) {
        int c = w * 16 + r;
        xt[((size_t)(b * 66 + (y + 1)) * 64 + c) * 66 + 1 + lane] = Xl[c * 65 + lane];
    }
}

// ---- Main GEMM: R6 structure + FUSED A-staging (feat8 on the fly) ----
// tile 64m(1 line) x 128n, FULL K (72 slabs), grid 512, block 512 (8 waves),
// 2 blocks/CU (72 KB LDS), XCD swizzle. Per phase: A = each wave loads 64
// x-scalars (256B coalesced from xt, L1/L2-hot), feat8, ds_write_b128 its
// chunk row (8 KB total); B = 16 KB via global_load_lds (2 wave-loads each).
// x-load pipelined 1 phase deep (xv for slab P+4 loaded at phase P).
// vmcnt: 2 B + 1 x per thread per phase -> steady gate vmcnt(5), tail 4/2/0.
#define BUF_SHORTS 12288

#define STAGE_B(sl, q_)                                                               \
    {                                                                                 \
        unsigned short* bufq = Bufs + (q_) * BUF_SHORTS;                              \
        const unsigned short* bsrc = wt + (size_t)(sl) * 8192;                        \
        _Pragma("unroll")                                                             \
        for (int t = 0; t < 2; ++t) {                                                 \
            int boff = (wave * 2 + t) * 512 + lane * 8;                               \
            __builtin_amdgcn_global_load_lds((g_u32_t*)(bsrc + boff),                 \
                                             (lds_u32_t*)(bufq + boff), 16, 0, 0);    \
        }                                                                             \
    }

#define XLOAD(sl)                                                                     \
    {                                                                                 \
        int ia  = (sl) * 8 + wave;                                                    \
        int c_  = (ia * 7282) >> 16;                                                  \
        int i9_ = ia - c_ * 9;                                                        \
        int kh_ = (i9_ * 11) >> 5;                                                    \
        int kw_ = i9_ - kh_ * 3;                                                      \
        xv = xt[((size_t)(b * 66 + y + kh_) * 64 + c_) * 66 + kw_ + lane];            \
    }

#define STAGE_A_WRITE(q_)                                                             \
    {                                                                                 \
        unsigned short* bufq = Bufs + (q_) * BUF_SHORTS;                              \
        union { unsigned short u[8]; uint4 v; } pk;                                   \
        feat8(xv, pk.u);                                                              \
        *(uint4*)(bufq + 8192 + wave * 512 + lane * 8) = pk.v;                        \
    }

#define COMPUTE(q_)                                                                   \
    {                                                                                 \
        const unsigned short* bufr = Bufs + (q_) * BUF_SHORTS;                        \
        const unsigned short* Ab = bufr + 8192 + iloc * 512;                          \
        const unsigned short* Bb = bufr + iloc * 1024 + nh * 512;                     \
        short8 a0 = *(const short8*)(Ab + l32 * 8);                                   \
        short8 a1 = *(const short8*)(Ab + (32 + l32) * 8);                            \
        short8 b0 = *(const short8*)(Bb + l32 * 8);                                   \
        short8 b1 = *(const short8*)(Bb + 256 + l32 * 8);                             \
        acc00 = __builtin_amdgcn_mfma_f32_32x32x16_bf16(a0, b0, acc00, 0, 0, 0);      \
        acc01 = __builtin_amdgcn_mfma_f32_32x32x16_bf16(a0, b1, acc01, 0, 0, 0);      \
        acc10 = __builtin_amdgcn_mfma_f32_32x32x16_bf16(a1, b0, acc10, 0, 0, 0);      \
        acc11 = __builtin_amdgcn_mfma_f32_32x32x16_bf16(a1, b1, acc11, 0, 0, 0);      \
    }

#define PHASE(q_, n_, stagesl, dostage_, doxl_)                                       \
    {                                                                                 \
        asm volatile("s_waitcnt vmcnt(" #n_ ") lgkmcnt(0)" ::: "memory");             \
        __builtin_amdgcn_s_barrier();                                                 \
        asm volatile("" ::: "memory");                                                \
        __builtin_amdgcn_s_setprio(1);                                                \
        COMPUTE(q_)                                                                   \
        __builtin_amdgcn_s_setprio(0);                                                \
        asm volatile("" ::: "memory");                                                \
        __builtin_amdgcn_s_barrier();                                                 \
        asm volatile("" ::: "memory");                                                \
        if (dostage_) {                                                               \
            STAGE_A_WRITE(q_)                                                         \
            if (doxl_) XLOAD((stagesl) + 1)                                           \
            STAGE_B(stagesl, q_)                                                      \
        }                                                                             \
    }

// Epilogue reduce helpers: conflict-free float4 layout (lane-stride 16 B).
#define DUMPA(base_, A_)                                                              \
    {   float4* s4 = (float4*)(red + (base_));                                        \
        _Pragma("unroll")                                                             \
        for (int c = 0; c < 4; ++c)                                                   \
            s4[c * 64 + lane] = make_float4(A_[4*c], A_[4*c+1], A_[4*c+2], A_[4*c+3]); }
#define ADDA(base_, A_)                                                               \
    {   const float4* s4 = (const float4*)(red + (base_));                            \
        _Pragma("unroll")                                                             \
        for (int c = 0; c < 4; ++c) {                                                 \
            float4 rv = s4[c * 64 + lane];                                            \
            A_[4*c] += rv.x; A_[4*c+1] += rv.y; A_[4*c+2] += rv.z; A_[4*c+3] += rv.w; } }

__global__ __launch_bounds__(512, 4)
void convkan_gemm(const float* __restrict__ xt,
                  const unsigned short* __restrict__ wt,
                  const float* __restrict__ bias,
                  float* __restrict__ out) {
    extern __shared__ unsigned short Bufs[];     // 3 x 12288 shorts = 72 KB

    const int tid  = threadIdx.x;
    const int blk  = blockIdx.x;                 // 0..511
    const int mb   = ((blk & 7) << 6) | (blk >> 3);  // XCD swizzle: XCD owns image
    const int lane = tid & 63;
    const int wave = tid >> 6;                   // 0..7 (= A chunk this wave stages)
    const int kq   = wave >> 1;                  // K-quarter 0..3
    const int nh   = wave & 1;                   // n-half (64 ch)
    const int l32  = lane & 31;
    const int h    = lane >> 5;                  // k-half within MFMA K16
    const int iloc = (kq << 1) + h;              // e-chunk this half-wave consumes

    const int b = mb >> 6;                       // image 0..7
    const int y = mb & 63;                       // line 0..63

    f32x16 acc00, acc01, acc10, acc11;
#pragma unroll
    for (int e = 0; e < 16; ++e) { acc00[e] = 0.f; acc01[e] = 0.f; acc10[e] = 0.f; acc11[e] = 0.f; }

    float xv;

    // prologue: fill the 3-deep pipeline (slabs 0,1,2), then x for slab 3
    XLOAD(0) STAGE_A_WRITE(0) STAGE_B(0, 0)
    XLOAD(1) STAGE_A_WRITE(1) STAGE_B(1, 1)
    XLOAD(2) STAGE_A_WRITE(2) STAGE_B(2, 2)
    XLOAD(3)

    // steady state: phases 0..65 (stage slabs 3..68, x-load slabs 4..69)
    for (int it3 = 0; it3 < 22; ++it3) {
        const int it = it3 * 3;
        PHASE(0, 5, it + 3, true, true)
        PHASE(1, 5, it + 4, true, true)
        PHASE(2, 5, it + 5, true, true)
    }
    // phases 66..68: stage 69,70,71 (x-load 70,71, then stop)
    PHASE(0, 5, 69, true, true)
    PHASE(1, 5, 70, true, true)
    PHASE(2, 5, 71, true, false)
    // phases 69..71: drain
    PHASE(0, 4, 0, false, false)
    PHASE(1, 2, 0, false, false)
    PHASE(2, 0, 0, false, false)

    // ---- K-partial reduction across kq (3 rounds via LDS), then store ----
    __syncthreads();
    float* red = (float*)Bufs;

    if (kq >= 2) { DUMPA(((nh << 1) + (kq - 2)) * 2048,        acc00);
                   DUMPA(((nh << 1) + (kq - 2)) * 2048 + 1024, acc01); }
    __syncthreads();
    if (kq < 2)  { ADDA(((nh << 1) + kq) * 2048,        acc00);
                   ADDA(((nh << 1) + kq) * 2048 + 1024, acc01); }
    __syncthreads();
    if (kq >= 2) { DUMPA(((nh << 1) + (kq - 2)) * 2048,        acc10);
                   DUMPA(((nh << 1) + (kq - 2)) * 2048 + 1024, acc11); }
    __syncthreads();
    if (kq < 2)  { ADDA(((nh << 1) + kq) * 2048,        acc10);
                   ADDA(((nh << 1) + kq) * 2048 + 1024, acc11); }
    __syncthreads();
    if (kq == 1) { DUMPA(nh * 4096,        acc00); DUMPA(nh * 4096 + 1024, acc01);
                   DUMPA(nh * 4096 + 2048, acc10); DUMPA(nh * 4096 + 3072, acc11); }
    __syncthreads();
    if (kq == 0) {
        ADDA(nh * 4096,        acc00); ADDA(nh * 4096 + 1024, acc01);
        ADDA(nh * 4096 + 2048, acc10); ADDA(nh * 4096 + 3072, acc11);

        const int ncol = nh * 64 + l32;
        const float bv0 = bias[ncol];
        const float bv1 = bias[ncol + 32];
        const int prow = mb * 64;                // output pixel-row base
#pragma unroll
        for (int r = 0; r < 16; ++r) {
            int mrow = (r & 3) + ((r >> 2) << 3) + 4 * h;
            float* p = out + (size_t)(prow + mrow) * 128 + ncol;
            p[0]  = acc00[r] + bv0;
            p[32] = acc01[r] + bv1;
            float* p2 = out + (size_t)(prow + 32 + mrow) * 128 + ncol;
            p2[0]  = acc10[r] + bv0;
            p2[32] = acc11[r] + bv1;
        }
    }
}

extern "C" void kernel_launch(void* const* d_in, const int* in_sizes, int n_in,
                              void* d_out, int out_size, void* d_ws, size_t ws_size,
                              hipStream_t stream) {
    (void)in_sizes; (void)n_in; (void)ws_size; (void)out_size;
    const float* x        = (const float*)d_in[0];
    const float* base_w   = (const float*)d_in[1];
    const float* spline_w = (const float*)d_in[2];
    const float* bias     = (const float*)d_in[3];
    float* out = (float*)d_out;

    float* xt          = (float*)d_ws;               // 8.92 MB transposed x (halo=0)
    unsigned short* wt = (unsigned short*)(xt + XT_FLOATS);  // 2.36 MB tiled B

    hipMemsetAsync(xt, 0, XT_FLOATS * sizeof(float), stream);
    hipLaunchKernelGGL(prep_all, dim3(512), dim3(256), 0, stream,
                       x, base_w, spline_w, xt, wt);

    const int shmem = 3 * BUF_SHORTS * 2;            // 72 KB -> 2 blocks/CU
    (void)hipFuncSetAttribute((const void*)convkan_gemm,
                              hipFuncAttributeMaxDynamicSharedMemorySize, shmem);
    hipLaunchKernelGGL(convkan_gemm, dim3(512), dim3(512), shmem, stream,
                       xt, wt, bias, out);
}